// Round 4
// baseline (195.239 us; speedup 1.0000x reference)
//
#include <hip/hip_runtime.h>

#define NN 4096
#define C 256
#define NH 4
#define CH 64
#define JSPLIT 8
#define JSLICE (NN / JSPLIT)     // 512
#define NJT (JSLICE / 32)        // 16

typedef float f32x4 __attribute__((ext_vector_type(4)));
typedef __bf16 b16x8 __attribute__((ext_vector_type(8)));
typedef unsigned short u16x8 __attribute__((ext_vector_type(8)));
typedef unsigned int u32x4 __attribute__((ext_vector_type(4)));

__device__ inline float fast_exp2(float x) {
#if __has_builtin(__builtin_amdgcn_exp2f)
  return __builtin_amdgcn_exp2f(x);
#else
  return exp2f(x);
#endif
}

// pack two f32 -> (bf16(f0) | bf16(f1)<<16), round-half-up via +0x8000, v_perm pack
__device__ inline unsigned pack2bf(float f0, float f1) {
  unsigned u0 = __float_as_uint(f0) + 0x8000u;
  unsigned u1 = __float_as_uint(f1) + 0x8000u;
  return __builtin_amdgcn_perm(u1, u0, 0x07060302u);  // low half <- u0.hi, high <- u1.hi
}

// ---------------- Kernel 0: prep — pack adj to bits, X->bf16, W->bf16 transposed
__global__ __launch_bounds__(256) void k_prep(
    const int* __restrict__ adj, const float* __restrict__ X,
    const float* __restrict__ W, unsigned char* __restrict__ packed,
    unsigned short* __restrict__ Xbf, unsigned short* __restrict__ WT) {
  const int b = blockIdx.x, t = threadIdx.x;
  if (b < 8192) {
    // adj bit-pack: thread -> one output byte = 8 adjacency ints
    const int idx = b * 256 + t;
    const int4 a0 = *(const int4*)(adj + (size_t)idx * 8);
    const int4 a1 = *(const int4*)(adj + (size_t)idx * 8 + 4);
    unsigned m = 0;
    m |= (a0.x != 0) ? 1u : 0u;   m |= (a0.y != 0) ? 2u : 0u;
    m |= (a0.z != 0) ? 4u : 0u;   m |= (a0.w != 0) ? 8u : 0u;
    m |= (a1.x != 0) ? 16u : 0u;  m |= (a1.y != 0) ? 32u : 0u;
    m |= (a1.z != 0) ? 64u : 0u;  m |= (a1.w != 0) ? 128u : 0u;
    packed[idx] = (unsigned char)m;
  } else if (b < 9216) {
    // X fp32 -> bf16 row-major
    const int idx = (b - 8192) * 256 + t;
    const float4 v = ((const float4*)X)[idx];
    uint2 st;
    st.x = pack2bf(v.x, v.y);
    st.y = pack2bf(v.z, v.w);
    ((uint2*)Xbf)[idx] = st;
  } else {
    // W fp32 -> bf16 transposed: WT[c][k] = W[k][c]; coalesced writes
    const int c = b - 9216;          // 0..255
    const float w = W[(size_t)t * C + c];
    WT[(size_t)c * C + t] = (unsigned short)((__float_as_uint(w) + 0x8000u) >> 16);
  }
}

// ---------------- Kernel 1: feats = X@W + b via MFMA; fused src/dst/featsT epilogue
__global__ __launch_bounds__(256) void k_feats(
    const unsigned short* __restrict__ Xbf, const unsigned short* __restrict__ WT,
    const float* __restrict__ bias, const float* __restrict__ av,
    unsigned short* __restrict__ featsT, float* __restrict__ srcv,
    float* __restrict__ dstT) {
  const int i0 = blockIdx.x * 16;
  const int h = threadIdx.x >> 6;        // wave = head = 64-col group
  const int lane = threadIdx.x & 63;
  const int q = lane >> 4, n = lane & 15;
  const int c0 = h * CH;

  const f32x4 zero = {0.f, 0.f, 0.f, 0.f};
  f32x4 acc[4];
#pragma unroll
  for (int g = 0; g < 4; ++g) acc[g] = zero;

  const unsigned short* ap = Xbf + (size_t)(i0 + n) * C + q * 8;
#pragma unroll
  for (int kt = 0; kt < 8; ++kt) {
    const b16x8 aF = __builtin_bit_cast(b16x8, *(const u16x8*)(ap + kt * 32));
#pragma unroll
    for (int g = 0; g < 4; ++g) {
      const b16x8 bF = __builtin_bit_cast(b16x8,
          *(const u16x8*)(WT + (size_t)(c0 + g * 16 + n) * C + kt * 32 + q * 8));
      acc[g] = __builtin_amdgcn_mfma_f32_16x16x32_bf16(aF, bF, acc[g], 0, 0, 0);
    }
  }

  float fb[4][4], asv[4], adv[4];
#pragma unroll
  for (int g = 0; g < 4; ++g) {
    const float bs = bias[c0 + g * 16 + n];
    asv[g] = av[h * 128 + g * 16 + n];
    adv[g] = av[h * 128 + 64 + g * 16 + n];
#pragma unroll
    for (int r = 0; r < 4; ++r) fb[g][r] = acc[g][r] + bs;
  }
  // featsT[c][i] bf16, 4 rows packed per store
#pragma unroll
  for (int g = 0; g < 4; ++g) {
    uint2 st;
    st.x = pack2bf(fb[g][0], fb[g][1]);
    st.y = pack2bf(fb[g][2], fb[g][3]);
    *(uint2*)(featsT + (size_t)(c0 + g * 16 + n) * NN + i0 + q * 4) = st;
  }
  // src/dst: per row r (row = i0+q*4+r), reduce over g in-lane, over n by shfl
#pragma unroll
  for (int r = 0; r < 4; ++r) {
    float p = 0.f, d = 0.f;
#pragma unroll
    for (int g = 0; g < 4; ++g) {
      p = fmaf(fb[g][r], asv[g], p);
      d = fmaf(fb[g][r], adv[g], d);
    }
#pragma unroll
    for (int m = 1; m < 16; m <<= 1) {
      p += __shfl_xor(p, m);
      d += __shfl_xor(d, m);
    }
    if (n == 0) {
      const int row = i0 + q * 4 + r;
      srcv[(size_t)row * NH + h] = p;
      dstT[(size_t)h * NN + row] = d;
    }
  }
}

// ---------------- Kernel 2: masked-softmax attention + PV via MFMA
// wave = 16 rows x 1 head; block = 4 waves (4 heads, shared adj bits via L1).
// grid (8 slices, 256 i-tiles) = 8192 waves = 8 waves/SIMD available.
// Softmax shift = leaky(s+16) (upper bound; cancels exactly). l via MFMA(B=ones).
__global__ __launch_bounds__(256, 6) void k_attn(
    const unsigned char* __restrict__ packed,
    const unsigned short* __restrict__ featsT,
    const float* __restrict__ srcv, const float* __restrict__ dstT,
    _Float16* __restrict__ pacc, float* __restrict__ lpart) {
  const int slice = blockIdx.x;
  const int i0 = blockIdx.y * 16;
  const int h = threadIdx.x >> 6;
  const int lane = threadIdx.x & 63;
  const int q = lane >> 4, n = lane & 15;
  const int jbase = slice * JSLICE;
  const int row = i0 + n;

  const float LOG2E = 1.4426950408889634f;
  const float s0 = srcv[(size_t)row * NH + h];
  const float xm0 = s0 + 16.0f;
  const float m20 = fmaxf(xm0, 0.2f * xm0) * LOG2E;

  const f32x4 zero = {0.f, 0.f, 0.f, 0.f};
  f32x4 acc[4], lacc = zero;
#pragma unroll
  for (int g = 0; g < 4; ++g) acc[g] = zero;

  u16x8 ou;
#pragma unroll
  for (int jj = 0; jj < 8; ++jj) ou[jj] = 0x3F80;  // bf16 1.0
  const b16x8 ones = __builtin_bit_cast(b16x8, ou);

  const unsigned char* mp = packed + (size_t)row * 512 + (jbase >> 3) + q;
  const float* dp = dstT + (size_t)h * NN + jbase + q * 8;
  const unsigned short* fp0 = featsT + (size_t)(h * CH + n) * NN + jbase + q * 8;

  // prologue: jt=0 mask + dst
  unsigned Mb = mp[0];
  float4 d0 = *(const float4*)dp;
  float4 d1 = *(const float4*)(dp + 4);

  for (int jt = 0; jt < NJT; ++jt) {
    // (1) issue this jt's B-fragment loads first (L2 latency covered by E calc)
    b16x8 bF[4];
#pragma unroll
    for (int g = 0; g < 4; ++g)
      bF[g] = __builtin_bit_cast(b16x8,
          *(const u16x8*)(fp0 + (size_t)(g * 16) * NN + jt * 32));

    // (2) prefetch next jt's mask + dst
    const int nx = (jt + 1 < NJT) ? jt + 1 : jt;
    const unsigned Mbn = mp[nx * 4];
    const float4 d0n = *(const float4*)(dp + nx * 32);
    const float4 d1n = *(const float4*)(dp + nx * 32 + 4);

    // (3) compute E (pure VALU)
    const float dv[8] = {d0.x, d0.y, d0.z, d0.w, d1.x, d1.y, d1.z, d1.w};
    u32x4 pk;
#pragma unroll
    for (int p = 0; p < 4; ++p) {
      const int j0 = 2 * p, j1 = 2 * p + 1;
      float x, a;
      x = s0 + dv[j0]; a = fmaf(fmaxf(x, 0.2f * x), LOG2E, -m20);
      const float e0 = fast_exp2((Mb & (1u << j0)) ? a : -200.0f);
      x = s0 + dv[j1]; a = fmaf(fmaxf(x, 0.2f * x), LOG2E, -m20);
      const float e1 = fast_exp2((Mb & (1u << j1)) ? a : -200.0f);
      pk[p] = pack2bf(e0, e1);
    }
    const b16x8 E = __builtin_bit_cast(b16x8, pk);

    // (4) MFMA
#pragma unroll
    for (int g = 0; g < 4; ++g)
      acc[g] = __builtin_amdgcn_mfma_f32_16x16x32_bf16(E, bF[g], acc[g], 0, 0, 0);
    lacc = __builtin_amdgcn_mfma_f32_16x16x32_bf16(E, ones, lacc, 0, 0, 0);

    Mb = Mbn; d0 = d0n; d1 = d1n;
  }

#pragma unroll
  for (int g = 0; g < 4; ++g)
#pragma unroll
    for (int r = 0; r < 4; ++r) {
      const int col = h * CH + g * 16 + n;
      pacc[((size_t)slice * NN + i0 + q * 4 + r) * C + col] = (_Float16)acc[g][r];
    }
  if (n == 0) {
#pragma unroll
    for (int r = 0; r < 4; ++r)
      lpart[((size_t)slice * NN + i0 + q * 4 + r) * NH + h] = lacc[r];
  }
}

// ---------------- Kernel 3: combine j-slices, divide
__global__ __launch_bounds__(256) void k_final(
    const _Float16* __restrict__ pacc, const float* __restrict__ lpart,
    float* __restrict__ out) {
  const int i = blockIdx.x;
  const int c = threadIdx.x;
  const int h = c >> 6;
  float l = 0.f, sa = 0.f;
#pragma unroll
  for (int sp = 0; sp < JSPLIT; ++sp) {
    l += lpart[((size_t)sp * NN + i) * NH + h];
    sa += (float)pacc[((size_t)sp * NN + i) * C + c];
  }
  out[(size_t)i * C + c] = sa / l;
}

extern "C" void kernel_launch(void* const* d_in, const int* in_sizes, int n_in,
                              void* d_out, int out_size, void* d_ws, size_t ws_size,
                              hipStream_t stream) {
  const float* nf   = (const float*)d_in[0];
  const int* adj    = (const int*)d_in[1];
  const float* W    = (const float*)d_in[2];
  const float* bias = (const float*)d_in[3];
  const float* av   = (const float*)d_in[4];
  float* out = (float*)d_out;

  char* ws = (char*)d_ws;
  unsigned char* packed  = (unsigned char*)ws;                         // 2 MB
  unsigned short* Xbf    = (unsigned short*)(ws + (2u << 20));         // 2 MB
  unsigned short* WT     = (unsigned short*)(ws + (4u << 20));         // 128 KB
  unsigned short* featsT = (unsigned short*)(ws + (4u << 20) + (256u << 10)); // 2 MB
  float* srcv  = (float*)(ws + (6u << 20) + (256u << 10));             // 64 KB
  float* dstT  = (float*)(ws + (6u << 20) + (320u << 10));             // 64 KB
  float* lpart = (float*)(ws + (6u << 20) + (384u << 10));             // 512 KB
  _Float16* pacc = (_Float16*)(ws + (8u << 20));                       // 16 MB

  k_prep<<<9472, 256, 0, stream>>>(adj, nf, W, packed, Xbf, WT);
  k_feats<<<NN / 16, 256, 0, stream>>>(Xbf, WT, bias, av, featsT, srcv, dstT);
  dim3 g2(JSPLIT, NN / 16);
  k_attn<<<g2, 256, 0, stream>>>(packed, featsT, srcv, dstT, pacc, lpart);
  k_final<<<NN, 256, 0, stream>>>(pacc, lpart, out);
}

// Round 5
// 139.892 us; speedup vs baseline: 1.3956x; 1.3956x over previous
//
#include <hip/hip_runtime.h>

#define NN 4096
#define C 256
#define NH 4
#define CH 64
#define JSPLIT 8
#define JSLICE (NN / JSPLIT)     // 512
#define NJT (JSLICE / 32)        // 16

typedef float f32x4 __attribute__((ext_vector_type(4)));
typedef __bf16 b16x8 __attribute__((ext_vector_type(8)));
typedef unsigned short u16x8 __attribute__((ext_vector_type(8)));
typedef unsigned int u32x4 __attribute__((ext_vector_type(4)));

__device__ inline float fast_exp2(float x) {
#if __has_builtin(__builtin_amdgcn_exp2f)
  return __builtin_amdgcn_exp2f(x);
#else
  return exp2f(x);
#endif
}

// pack two f32 -> (bf16(f0) | bf16(f1)<<16), round-half-up via +0x8000, v_perm pack
__device__ inline unsigned pack2bf(float f0, float f1) {
  unsigned u0 = __float_as_uint(f0) + 0x8000u;
  unsigned u1 = __float_as_uint(f1) + 0x8000u;
  return __builtin_amdgcn_perm(u1, u0, 0x07060302u);
}

// ---------------- Kernel 0: prep — pack adj to bits, X->bf16, W->bf16 transposed
__global__ __launch_bounds__(256) void k_prep(
    const int* __restrict__ adj, const float* __restrict__ X,
    const float* __restrict__ W, unsigned char* __restrict__ packed,
    unsigned short* __restrict__ Xbf, unsigned short* __restrict__ WT) {
  const int b = blockIdx.x, t = threadIdx.x;
  if (b < 8192) {
    const int idx = b * 256 + t;
    const int4 a0 = *(const int4*)(adj + (size_t)idx * 8);
    const int4 a1 = *(const int4*)(adj + (size_t)idx * 8 + 4);
    unsigned m = 0;
    m |= (a0.x != 0) ? 1u : 0u;   m |= (a0.y != 0) ? 2u : 0u;
    m |= (a0.z != 0) ? 4u : 0u;   m |= (a0.w != 0) ? 8u : 0u;
    m |= (a1.x != 0) ? 16u : 0u;  m |= (a1.y != 0) ? 32u : 0u;
    m |= (a1.z != 0) ? 64u : 0u;  m |= (a1.w != 0) ? 128u : 0u;
    packed[idx] = (unsigned char)m;
  } else if (b < 9216) {
    const int idx = (b - 8192) * 256 + t;
    const float4 v = ((const float4*)X)[idx];
    uint2 st;
    st.x = pack2bf(v.x, v.y);
    st.y = pack2bf(v.z, v.w);
    ((uint2*)Xbf)[idx] = st;
  } else {
    const int c = b - 9216;
    const float w = W[(size_t)t * C + c];
    WT[(size_t)c * C + t] = (unsigned short)((__float_as_uint(w) + 0x8000u) >> 16);
  }
}

// ---------------- Kernel 1: feats = X@W + b via MFMA; epilogue stores
// B-fragment-major tiles F[jt][h][g][lane]*8bf16, src, dstT2={d*L, .2d*L}
__global__ __launch_bounds__(256) void k_feats(
    const unsigned short* __restrict__ Xbf, const unsigned short* __restrict__ WT,
    const float* __restrict__ bias, const float* __restrict__ av,
    unsigned short* __restrict__ F, float* __restrict__ srcv,
    float2* __restrict__ dstT2) {
  const int i0 = blockIdx.x * 16;
  const int h = threadIdx.x >> 6;
  const int lane = threadIdx.x & 63;
  const int q = lane >> 4, n = lane & 15;
  const int c0 = h * CH;
  const float LOG2E = 1.4426950408889634f;

  const f32x4 zero = {0.f, 0.f, 0.f, 0.f};
  f32x4 acc[4];
#pragma unroll
  for (int g = 0; g < 4; ++g) acc[g] = zero;

  const unsigned short* ap = Xbf + (size_t)(i0 + n) * C + q * 8;
#pragma unroll
  for (int kt = 0; kt < 8; ++kt) {
    const b16x8 aF = __builtin_bit_cast(b16x8, *(const u16x8*)(ap + kt * 32));
#pragma unroll
    for (int g = 0; g < 4; ++g) {
      const b16x8 bF = __builtin_bit_cast(b16x8,
          *(const u16x8*)(WT + (size_t)(c0 + g * 16 + n) * C + kt * 32 + q * 8));
      acc[g] = __builtin_amdgcn_mfma_f32_16x16x32_bf16(aF, bF, acc[g], 0, 0, 0);
    }
  }

  float fb[4][4], asv[4], adv[4];
#pragma unroll
  for (int g = 0; g < 4; ++g) {
    const float bs = bias[c0 + g * 16 + n];
    asv[g] = av[h * 128 + g * 16 + n];
    adv[g] = av[h * 128 + 64 + g * 16 + n];
#pragma unroll
    for (int r = 0; r < 4; ++r) fb[g][r] = acc[g][r] + bs;
  }
  // fragment-major store: tile (jt = i0>>5, h, g); j-in-tile = 16*half+4q+r
  const int jt = i0 >> 5, half = (i0 >> 4) & 1;
  const int qp = half * 2 + (q >> 1);          // q' in B-fragment
#pragma unroll
  for (int g = 0; g < 4; ++g) {
    uint2 st;
    st.x = pack2bf(fb[g][0], fb[g][1]);
    st.y = pack2bf(fb[g][2], fb[g][3]);
    *(uint2*)(F + ((size_t)((jt * NH + h) * 4 + g)) * 512 + (qp * 16 + n) * 8 + 4 * (q & 1)) = st;
  }
  // src/dst epilogue
#pragma unroll
  for (int r = 0; r < 4; ++r) {
    float p = 0.f, d = 0.f;
#pragma unroll
    for (int g = 0; g < 4; ++g) {
      p = fmaf(fb[g][r], asv[g], p);
      d = fmaf(fb[g][r], adv[g], d);
    }
#pragma unroll
    for (int m = 1; m < 16; m <<= 1) {
      p += __shfl_xor(p, m);
      d += __shfl_xor(d, m);
    }
    if (n == 0) {
      const int row = i0 + q * 4 + r;
      srcv[(size_t)row * NH + h] = p;
      const float dL = d * LOG2E;
      dstT2[(size_t)h * NN + row] = make_float2(dL, 0.2f * dL);
    }
  }
}

// ---------------- Kernel 2: masked-softmax attention + PV via MFMA
// wave = 32 rows x 1 head; coalesced fragment loads; mask via shfl-redistribute.
__global__ __launch_bounds__(256, 4) void k_attn(
    const unsigned char* __restrict__ packed,
    const unsigned short* __restrict__ F,
    const float* __restrict__ srcv, const float2* __restrict__ dstT2,
    _Float16* __restrict__ pacc, float* __restrict__ lpart) {
  const int slice = blockIdx.x;
  const int i0 = blockIdx.y * 32;
  const int h = threadIdx.x >> 6;
  const int lane = threadIdx.x & 63;
  const int q = lane >> 4, n = lane & 15;
  const int jbase = slice * JSLICE;

  const float LOG2E = 1.4426950408889634f;
  const int r0 = i0 + n, r1 = i0 + 16 + n;
  const float s0 = srcv[(size_t)r0 * NH + h];
  const float s1 = srcv[(size_t)r1 * NH + h];
  const float xm0 = s0 + 16.0f, xm1 = s1 + 16.0f;
  const float m20 = fmaxf(xm0, 0.2f * xm0) * LOG2E;
  const float m21 = fmaxf(xm1, 0.2f * xm1) * LOG2E;
  const float u0 = fmaf(s0, LOG2E, -m20), w0 = fmaf(0.2f * s0, LOG2E, -m20);
  const float u1 = fmaf(s1, LOG2E, -m21), w1 = fmaf(0.2f * s1, LOG2E, -m21);

  const f32x4 zero = {0.f, 0.f, 0.f, 0.f};
  f32x4 acc0[4], acc1[4], lacc0 = zero, lacc1 = zero;
#pragma unroll
  for (int g = 0; g < 4; ++g) { acc0[g] = zero; acc1[g] = zero; }

  u16x8 ou;
#pragma unroll
  for (int jj = 0; jj < 8; ++jj) ou[jj] = 0x3F80;
  const b16x8 ones = __builtin_bit_cast(b16x8, ou);

  // preload slice masks: lane (q,n) holds 16-byte chunk q of rows r0 / r1
  const u32x4 m40 = *(const u32x4*)(packed + (size_t)r0 * 512 + (jbase >> 3) + q * 16);
  const u32x4 m41 = *(const u32x4*)(packed + (size_t)r1 * 512 + (jbase >> 3) + q * 16);

  const float* dp2 = (const float*)(dstT2 + (size_t)h * NN + jbase);
  const unsigned short* fp = F + ((size_t)((jbase >> 5) * NH + h) * 4) * 512 + lane * 8;

#pragma unroll
  for (int a = 0; a < 4; ++a) {
#pragma unroll
    for (int b = 0; b < 4; ++b) {
      const int jt = a * 4 + b;
      // coalesced B-fragment loads: 4 x 1KB sequential
      b16x8 bF[4];
#pragma unroll
      for (int g = 0; g < 4; ++g)
        bF[g] = __builtin_bit_cast(b16x8,
            *(const u16x8*)(fp + (size_t)(jt * NH * 4 + g) * 512));

      // masks via shfl from preloaded chunks: byte (4b+q) of word b, src lane a*16+n
      const unsigned Mb0 = (unsigned(__shfl((int)m40[b], a * 16 + n)) >> (q * 8)) & 0xffu;
      const unsigned Mb1 = (unsigned(__shfl((int)m41[b], a * 16 + n)) >> (q * 8)) & 0xffu;

      // dst pairs {dL, .2dL} for this lane's 8 j's (broadcast loads)
      const float* dq = dp2 + jt * 64 + q * 16;
      const float4 dd0 = *(const float4*)(dq);
      const float4 dd1 = *(const float4*)(dq + 4);
      const float4 dd2 = *(const float4*)(dq + 8);
      const float4 dd3 = *(const float4*)(dq + 12);
      const float4 dd[4] = {dd0, dd1, dd2, dd3};

      u32x4 pk0, pk1;
#pragma unroll
      for (int k = 0; k < 4; ++k) {
        const float a00 = fmaxf(dd[k].x + u0, dd[k].y + w0);
        const float a01 = fmaxf(dd[k].z + u0, dd[k].w + w0);
        const float a10 = fmaxf(dd[k].x + u1, dd[k].y + w1);
        const float a11 = fmaxf(dd[k].z + u1, dd[k].w + w1);
        const float e00 = fast_exp2((Mb0 & (1u << (2 * k))) ? a00 : -200.0f);
        const float e01 = fast_exp2((Mb0 & (2u << (2 * k))) ? a01 : -200.0f);
        const float e10 = fast_exp2((Mb1 & (1u << (2 * k))) ? a10 : -200.0f);
        const float e11 = fast_exp2((Mb1 & (2u << (2 * k))) ? a11 : -200.0f);
        pk0[k] = pack2bf(e00, e01);
        pk1[k] = pack2bf(e10, e11);
      }
      const b16x8 E0 = __builtin_bit_cast(b16x8, pk0);
      const b16x8 E1 = __builtin_bit_cast(b16x8, pk1);
#pragma unroll
      for (int g = 0; g < 4; ++g) {
        acc0[g] = __builtin_amdgcn_mfma_f32_16x16x32_bf16(E0, bF[g], acc0[g], 0, 0, 0);
        acc1[g] = __builtin_amdgcn_mfma_f32_16x16x32_bf16(E1, bF[g], acc1[g], 0, 0, 0);
      }
      lacc0 = __builtin_amdgcn_mfma_f32_16x16x32_bf16(E0, ones, lacc0, 0, 0, 0);
      lacc1 = __builtin_amdgcn_mfma_f32_16x16x32_bf16(E1, ones, lacc1, 0, 0, 0);
    }
  }

#pragma unroll
  for (int g = 0; g < 4; ++g)
#pragma unroll
    for (int r = 0; r < 4; ++r) {
      const int col = h * CH + g * 16 + n;
      pacc[((size_t)slice * NN + i0 + q * 4 + r) * C + col] = (_Float16)acc0[g][r];
      pacc[((size_t)slice * NN + i0 + 16 + q * 4 + r) * C + col] = (_Float16)acc1[g][r];
    }
  if (n == 0) {
#pragma unroll
    for (int r = 0; r < 4; ++r) {
      lpart[((size_t)slice * NN + i0 + q * 4 + r) * NH + h] = lacc0[r];
      lpart[((size_t)slice * NN + i0 + 16 + q * 4 + r) * NH + h] = lacc1[r];
    }
  }
}

// ---------------- Kernel 3: combine j-slices, divide
__global__ __launch_bounds__(256) void k_final(
    const _Float16* __restrict__ pacc, const float* __restrict__ lpart,
    float* __restrict__ out) {
  const int i = blockIdx.x;
  const int c = threadIdx.x;
  const int h = c >> 6;
  float l = 0.f, sa = 0.f;
#pragma unroll
  for (int sp = 0; sp < JSPLIT; ++sp) {
    l += lpart[((size_t)sp * NN + i) * NH + h];
    sa += (float)pacc[((size_t)sp * NN + i) * C + c];
  }
  out[(size_t)i * C + c] = sa / l;
}

extern "C" void kernel_launch(void* const* d_in, const int* in_sizes, int n_in,
                              void* d_out, int out_size, void* d_ws, size_t ws_size,
                              hipStream_t stream) {
  const float* nf   = (const float*)d_in[0];
  const int* adj    = (const int*)d_in[1];
  const float* W    = (const float*)d_in[2];
  const float* bias = (const float*)d_in[3];
  const float* av   = (const float*)d_in[4];
  float* out = (float*)d_out;

  char* ws = (char*)d_ws;
  unsigned char* packed  = (unsigned char*)ws;                              // 2 MB
  unsigned short* Xbf    = (unsigned short*)(ws + (2u << 20));              // 2 MB
  unsigned short* WT     = (unsigned short*)(ws + (4u << 20));              // 128 KB
  unsigned short* F      = (unsigned short*)(ws + (4u << 20) + (256u << 10)); // 2 MB
  float* srcv   = (float*)(ws + (6u << 20) + (256u << 10));                 // 64 KB
  float2* dstT2 = (float2*)(ws + (6u << 20) + (320u << 10));                // 128 KB
  float* lpart  = (float*)(ws + (6u << 20) + (448u << 10));                 // 512 KB
  _Float16* pacc = (_Float16*)(ws + (8u << 20));                            // 16 MB

  k_prep<<<9472, 256, 0, stream>>>(adj, nf, W, packed, Xbf, WT);
  k_feats<<<NN / 16, 256, 0, stream>>>(Xbf, WT, bias, av, F, srcv, dstT2);
  dim3 g2(JSPLIT, NN / 32);
  k_attn<<<g2, 256, 0, stream>>>(packed, F, srcv, dstT2, pacc, lpart);
  k_final<<<NN, 256, 0, stream>>>(pacc, lpart, out);
}